// Round 1
// baseline (468.094 us; speedup 1.0000x reference)
//
#include <hip/hip_runtime.h>

#define NEGF (-1e30f)

// reduce across the 4 lanes of one matrix column (lanes 4m..4m+3)
__device__ __forceinline__ float colmax(float v) {
  v = fmaxf(v, __shfl_xor(v, 1));
  v = fmaxf(v, __shfl_xor(v, 2));
  return v;
}
__device__ __forceinline__ float colsum(float v) {
  v += __shfl_xor(v, 1);
  v += __shfl_xor(v, 2);
  return v;
}

struct Step {
  float beta[4], cont[4], start[4], al[4];
};

// Load one time-step's per-lane slice: rows k = 4r..4r+3.
__device__ __forceinline__ void load_step(
    const float* __restrict__ actl, const float* __restrict__ stopl,
    const float* __restrict__ startl, long bt /* batch*Tp1 + i */, int aidx,
    int A, int r, Step& s)
{
  const float4* sp = reinterpret_cast<const float4*>(stopl + bt * 32 + r * 8);
  float4 s0 = sp[0];
  float4 s1 = sp[1];
  s.beta[0] = s0.x; s.cont[0] = s0.y; s.beta[1] = s0.z; s.cont[1] = s0.w;
  s.beta[2] = s1.x; s.cont[2] = s1.y; s.beta[3] = s1.z; s.cont[3] = s1.w;
  float4 st = *reinterpret_cast<const float4*>(startl + bt * 16 + r * 4);
  s.start[0] = st.x; s.start[1] = st.y; s.start[2] = st.z; s.start[3] = st.w;
  const float* ap = actl + bt * (16L * A) + (long)(r * 4) * A + aidx;
  s.al[0] = ap[0];
  s.al[1] = ap[A];
  s.al[2] = ap[2 * A];
  s.al[3] = ap[3 * A];
}

// Kernel 1: one wave per (batch, chunk). Builds the 16x16 log-space transfer
// matrix for the chunk's time steps. Lane l: column m = l>>2, rows 4r..4r+3
// (r = l&3). Matrix kept column-normalized (Mn), per-column offset `off`.
// Update (exact rewrite of reference step in the log semiring):
//   S[m]     = lse_j(beta[j] + M[j,m])
//   M'[k,m]  = al[k] + logaddexp(start[k] + S[m], cont[k] + M[k,m])
// computed in the normalized frame as:
//   Mn'[k,m] = al[k] + log( s*exp(start[k]) + exp(cont[k] + Mn[k,m] - cmax) )
//   off     += cmax,  with s = sum_j exp(beta[j] + Mn[j,m] - cmax)
__global__ __launch_bounds__(256) void hmm_chunks(
    const float* __restrict__ action_logps,
    const float* __restrict__ stop_logps,
    const float* __restrict__ start_logps,
    const int* __restrict__ actions,
    const int* __restrict__ lengths,
    float* __restrict__ Mws, float* __restrict__ Offws,
    int B, int maxT, int A, int NC, int CHUNK)
{
  const int lane = threadIdx.x & 63;
  const int gw = blockIdx.x * (blockDim.x >> 6) + (threadIdx.x >> 6);
  if (gw >= B * NC) return;
  const int batch = gw / NC;
  const int chunk = gw % NC;
  const long Tp1 = (long)maxT + 1;
  const int m = lane >> 2;
  const int r = lane & 3;

  float M[4];
#pragma unroll
  for (int q = 0; q < 4; ++q) M[q] = (4 * r + q == m) ? 0.f : NEGF;
  float off = 0.f;

  const int len = lengths[batch];
  const int i0 = 1 + chunk * CHUNK;
  int i1 = i0 + CHUNK;
  if (i1 > maxT) i1 = maxT;     // reference scan runs i = 1 .. maxT-1
  if (i1 > len) i1 = len;       // mask: update only while i < length

  if (i0 < i1) {
    const int* actp = actions + (long)batch * maxT;
    const long bt0 = (long)batch * Tp1;
    Step cur, nxt;
    int aidx1;
    {
      int aidx0 = actp[i0];
      load_step(action_logps, stop_logps, start_logps, bt0 + i0, aidx0, A, r, cur);
      aidx1 = (i0 + 1 < i1) ? actp[i0 + 1] : 0;
    }
    for (int i = i0; i < i1; ++i) {
      const bool more = (i + 1 < i1);
      if (more)
        load_step(action_logps, stop_logps, start_logps, bt0 + i + 1, aidx1, A, r, nxt);
      const int aidx2 = (i + 2 < i1) ? actp[i + 2] : 0;

      // column max (normalization shift)
      float cmax = fmaxf(fmaxf(M[0], M[1]), fmaxf(M[2], M[3]));
      cmax = colmax(cmax);
      float Ms[4];
#pragma unroll
      for (int q = 0; q < 4; ++q) Ms[q] = M[q] - cmax;

      // s = sum_j exp(beta[j] + Mn[j,m] - cmax)
      float p = __expf(cur.beta[0] + Ms[0]) + __expf(cur.beta[1] + Ms[1]) +
                __expf(cur.beta[2] + Ms[2]) + __expf(cur.beta[3] + Ms[3]);
      const float ssum = colsum(p);

#pragma unroll
      for (int q = 0; q < 4; ++q) {
        const float e2 = __expf(cur.cont[q] + Ms[q]);
        const float es = __expf(cur.start[q]);
        M[q] = cur.al[q] + __logf(fmaxf(ssum * es + e2, 1e-37f));
      }
      off += cmax;

      cur = nxt;
      aidx1 = aidx2;
    }
  }

  // store: Mws[gw][m][k] (column-major: column m contiguous over k) + off per column
  float4 mv = make_float4(M[0], M[1], M[2], M[3]);
  *reinterpret_cast<float4*>(Mws + (long)gw * 256 + (m * 16 + r * 4)) = mv;
  if (r == 0) Offws[(long)gw * 16 + m] = off;
}

// Kernel 2: one wave per batch. f' [k] = lse_j( M_c[k,j] + off_c[j] + f[j] ),
// chunks applied in order; chunk matrices past `length` are identity so no
// masking needed here. Lane l: k = l&15, j-group jg = l>>4 (4 j's per lane).
__global__ __launch_bounds__(256) void hmm_combine(
    const float* __restrict__ action_logps,
    const float* __restrict__ stop_logps,
    const float* __restrict__ start_logps,
    const int* __restrict__ actions,
    const int* __restrict__ lengths,
    const float* __restrict__ Mws, const float* __restrict__ Offws,
    float* __restrict__ out,
    int B, int maxT, int A, int NC)
{
  const int batch = blockIdx.x * (blockDim.x >> 6) + (threadIdx.x >> 6);
  if (batch >= B) return;
  const int lane = threadIdx.x & 63;
  const int k = lane & 15;
  const int jg = lane >> 4;
  const long Tp1 = (long)maxT + 1;

  // f0[k] = start[b,0,k] + action_logps[b,0,k,a0]
  const int a0 = actions[(long)batch * maxT];
  float f = start_logps[(long)batch * Tp1 * 16 + k] +
            action_logps[(long)batch * Tp1 * (16L * A) + (long)k * A + a0];

  const float* Mb = Mws + (long)batch * NC * 256;
  const float* Ob = Offws + (long)batch * NC * 16;

  constexpr int PF = 4;  // prefetch depth (NC is a multiple of 4 by host construction)
  float pm[PF][4], po[PF][4];
#pragma unroll
  for (int d = 0; d < PF; ++d) {
#pragma unroll
    for (int q = 0; q < 4; ++q) {
      pm[d][q] = Mb[d * 256 + (4 * jg + q) * 16 + k];
      po[d][q] = Ob[d * 16 + 4 * jg + q];
    }
  }

  for (int cb = 0; cb < NC; cb += PF) {
#pragma unroll
    for (int u = 0; u < PF; ++u) {
      const int c = cb + u;
      float v[4];
      float mx = NEGF;
#pragma unroll
      for (int q = 0; q < 4; ++q) {
        const float fj = __shfl(f, 4 * jg + q);  // lane j holds f[j]
        v[q] = pm[u][q] + po[u][q] + fj;
        mx = fmaxf(mx, v[q]);
      }
      mx = fmaxf(mx, __shfl_xor(mx, 16));
      mx = fmaxf(mx, __shfl_xor(mx, 32));
      float s = 0.f;
#pragma unroll
      for (int q = 0; q < 4; ++q) s += __expf(v[q] - mx);
      s += __shfl_xor(s, 16);
      s += __shfl_xor(s, 32);
      f = mx + __logf(s);

      const int cn = c + PF;
      if (cn < NC) {
#pragma unroll
        for (int q = 0; q < 4; ++q) {
          pm[u][q] = Mb[(long)cn * 256 + (4 * jg + q) * 16 + k];
          po[u][q] = Ob[cn * 16 + 4 * jg + q];
        }
      }
    }
  }

  // finalize: total = lse_k( f[k] + stop[b, L, k, STOP] ); out += -total
  const int L = lengths[batch];
  const float st = stop_logps[((long)batch * Tp1 + L) * 32 + k * 2];
  const float v = f + st;
  float mx = v;
  mx = fmaxf(mx, __shfl_xor(mx, 1));
  mx = fmaxf(mx, __shfl_xor(mx, 2));
  mx = fmaxf(mx, __shfl_xor(mx, 4));
  mx = fmaxf(mx, __shfl_xor(mx, 8));
  float s = __expf(v - mx);
  s += __shfl_xor(s, 1);
  s += __shfl_xor(s, 2);
  s += __shfl_xor(s, 4);
  s += __shfl_xor(s, 8);
  const float tot = mx + __logf(s);
  if (lane == 0) atomicAdd(out, -tot);
}

extern "C" void kernel_launch(void* const* d_in, const int* in_sizes, int n_in,
                              void* d_out, int out_size, void* d_ws, size_t ws_size,
                              hipStream_t stream) {
  const float* action_logps = (const float*)d_in[0];
  const float* stop_logps = (const float*)d_in[1];
  const float* start_logps = (const float*)d_in[2];
  const int* actions = (const int*)d_in[3];
  const int* lengths = (const int*)d_in[4];

  const int B = in_sizes[4];
  const int maxT = in_sizes[3] / B;                       // actions: (B, maxT)
  const long Tp1 = (long)maxT + 1;
  const int b = (int)((long)in_sizes[1] / ((long)B * Tp1 * 2));  // must be 16
  const int A = (int)((long)in_sizes[0] / ((long)B * Tp1 * b));  // 18
  (void)b;

  int NC = 64;                                            // chunks over time
  const size_t per_chunk = (size_t)B * (256 + 16) * sizeof(float);
  if ((size_t)NC * per_chunk > ws_size) {                 // adapt to workspace
    NC = (int)(ws_size / per_chunk) & ~3;
    if (NC < 4) NC = 4;
  }
  const int CHUNK = (maxT - 1 + NC - 1) / NC;

  float* Mws = (float*)d_ws;                              // [B][NC][16][16]
  float* Offws = Mws + (size_t)B * NC * 256;              // [B][NC][16]

  hipMemsetAsync(d_out, 0, (size_t)out_size * sizeof(float), stream);

  const int nwaves = B * NC;
  hmm_chunks<<<dim3((nwaves + 3) / 4), dim3(256), 0, stream>>>(
      action_logps, stop_logps, start_logps, actions, lengths,
      Mws, Offws, B, maxT, A, NC, CHUNK);
  hmm_combine<<<dim3((B + 3) / 4), dim3(256), 0, stream>>>(
      action_logps, stop_logps, start_logps, actions, lengths,
      Mws, Offws, (float*)d_out, B, maxT, A, NC);
}